// Round 9
// baseline (721.764 us; speedup 1.0000x reference)
//
#include <hip/hip_runtime.h>
#include <math.h>

#define NB 256      // events
#define NSV 64
#define NTRK 512
#define NPFC 512
#define KNN 8
#define HD 32

__device__ __forceinline__ float elu_f(float x) {
    return x > 0.f ? x : __expf(x) - 1.f;
}

// Branchless sorted top-8 insert (ascending val, lower-index tie-break via
// strict <). Exactly equivalent to the r8 gated form (case-checked), but
// pure ternaries -> flat v_cmp + v_cndmask codegen, no exec-mask churn.
__device__ __forceinline__ void ins8(float dv, int s, float* val, int* idx) {
    bool c0 = dv < val[0], c1 = dv < val[1], c2 = dv < val[2], c3 = dv < val[3];
    bool c4 = dv < val[4], c5 = dv < val[5], c6 = dv < val[6], c7 = dv < val[7];
    val[7] = c6 ? val[6] : (c7 ? dv : val[7]);
    idx[7] = c6 ? idx[6] : (c7 ? s  : idx[7]);
    val[6] = c5 ? val[5] : (c6 ? dv : val[6]);
    idx[6] = c5 ? idx[5] : (c6 ? s  : idx[6]);
    val[5] = c4 ? val[4] : (c5 ? dv : val[5]);
    idx[5] = c4 ? idx[4] : (c5 ? s  : idx[5]);
    val[4] = c3 ? val[3] : (c4 ? dv : val[4]);
    idx[4] = c3 ? idx[3] : (c4 ? s  : idx[4]);
    val[3] = c2 ? val[2] : (c3 ? dv : val[3]);
    idx[3] = c2 ? idx[2] : (c3 ? s  : idx[3]);
    val[2] = c1 ? val[1] : (c2 ? dv : val[2]);
    idx[2] = c1 ? idx[1] : (c2 ? s  : idx[2]);
    val[1] = c0 ? val[0] : (c1 ? dv : val[1]);
    idx[1] = c0 ? idx[0] : (c1 ? s  : idx[1]);
    val[0] = c0 ? dv : val[0];
    idx[0] = c0 ? s  : idx[0];
}

// ---------------- encoder body (same math as validated rounds) -----------
template<int FIN>
__device__ void encode_body(const float* __restrict__ x,
                            const float* __restrict__ W1, const float* __restrict__ b1,
                            const float* __restrict__ W2, const float* __restrict__ b2,
                            float* __restrict__ out, int blk, int n_nodes)
{
    __shared__ float sW1[FIN * 32];
    __shared__ float sW2[32 * 32];
    __shared__ float sb1[32], sb2[32];
    __shared__ float sx[8][FIN];
    __shared__ float sh[8][32];
    int tid = threadIdx.x;
    for (int i = tid; i < FIN * 32; i += 256) sW1[i] = W1[i];
    for (int i = tid; i < 32 * 32; i += 256) sW2[i] = W2[i];
    if (tid < 32) { sb1[tid] = b1[tid]; sb2[tid] = b2[tid]; }
    int ln = tid >> 5, c = tid & 31;
    for (int it = 0; it < 4; it++) {
        int node0 = blk * 32 + it * 8;
        __syncthreads();
        for (int i = tid; i < 8 * FIN; i += 256) {
            int nn = i / FIN, f = i - nn * FIN;
            int node = node0 + nn;
            sx[nn][f] = (node < n_nodes) ? x[(size_t)node * FIN + f] : 0.f;
        }
        __syncthreads();
        float h = sb1[c];
#pragma unroll
        for (int f = 0; f < FIN; f++) h = fmaf(sx[ln][f], sW1[f * 32 + c], h);
        h = elu_f(h);
        sh[ln][c] = h;
        __syncthreads();
        float o = sb2[c];
#pragma unroll
        for (int k = 0; k < 32; k++) o = fmaf(sh[ln][k], sW2[k * 32 + c], o);
        o = elu_f(o);
        int node = node0 + ln;
        if (node < n_nodes) out[(size_t)node * 32 + c] = o;
    }
}

// ---------------- fused encoders + weight prep (1 launch) ----------------
__global__ __launch_bounds__(256) void encode_all_kernel(
    const float* __restrict__ x_sv, const float* __restrict__ x_trk, const float* __restrict__ x_pfc,
    const float* __restrict__ sv_W1, const float* __restrict__ sv_b1,
    const float* __restrict__ sv_W2, const float* __restrict__ sv_b2,
    const float* __restrict__ trk_W1, const float* __restrict__ trk_b1,
    const float* __restrict__ trk_W2, const float* __restrict__ trk_b2,
    const float* __restrict__ pfc_W1, const float* __restrict__ pfc_b1,
    const float* __restrict__ pfc_W2, const float* __restrict__ pfc_b2,
    const float* __restrict__ conv_W, const float* __restrict__ conv_b,
    float* __restrict__ sv_enc, float* __restrict__ trk_enc, float* __restrict__ pfc_enc,
    float* __restrict__ wd, float* __restrict__ w2h, float* __restrict__ bb)
{
    int bid = blockIdx.x;
    if (bid < 512) {
        encode_body<14>(x_sv, sv_W1, sv_b1, sv_W2, sv_b2, sv_enc, bid, NB * NSV);
    } else if (bid < 4608) {
        encode_body<30>(x_trk, trk_W1, trk_b1, trk_W2, trk_b2, trk_enc, bid - 512, NB * NTRK);
    } else if (bid < 8704) {
        encode_body<10>(x_pfc, pfc_W1, pfc_b1, pfc_W2, pfc_b2, pfc_enc, bid - 4608, NB * NPFC);
    } else {
        int tid = threadIdx.x;
        for (int i = tid; i < 1024; i += 256) {
            float lo = conv_W[i], hi = conv_W[1024 + i];
            wd[i] = lo - hi;
            w2h[i] = hi;
        }
        if (tid < 32) bb[tid] = conv_b[tid];
    }
}

// ---------------- Y/Base GEMM body (shared) ------------------------------
__device__ void yb_body(const float* __restrict__ X, const float* __restrict__ W,
                        const float* __restrict__ bias, float* __restrict__ O, int rb)
{
    __shared__ float sW[1024];
    __shared__ float sb[32];
    __shared__ float sx[8][32];
    int tid = threadIdx.x;
    for (int i = tid; i < 1024; i += 256) sW[i] = W[i];
    if (tid < 32) sb[tid] = bias ? bias[tid] : 0.f;
    int ln = tid >> 5, c = tid & 31;
    for (int p = 0; p < 8; p++) {
        __syncthreads();
        sx[ln][c] = X[(size_t)(rb + p * 8 + ln) * 32 + c];
        __syncthreads();
        float acc = sb[c];
#pragma unroll
        for (int d = 0; d < 32; d++) acc = fmaf(sx[ln][d], sW[d * 32 + c], acc);
        O[(size_t)(rb + p * 8 + ln) * 32 + c] = acc;
    }
}

// ---------------- small kNN body (NS=64, one block per event) -------------
__device__ void knn_small_body(const float* __restrict__ src, const float* __restrict__ dst,
                               int* __restrict__ idx_out, int b)
{
    constexpr int NS = 64;
    __shared__ float4 s_src[NS * 8];
    __shared__ float  s_nrm[NS];
    int tid = threadIdx.x;
    int lane = tid & 63;
    int wave = tid >> 6;

    const float4* src4 = (const float4*)(src + (size_t)b * NS * 32);
    for (int i = tid; i < NS * 8; i += 256) s_src[i] = src4[i];
    __syncthreads();
    if (tid < NS) {
        float a = 0.f;
#pragma unroll
        for (int q = 0; q < 8; q++) {
            float4 v = s_src[tid * 8 + q];
            a = fmaf(v.x, v.x, a); a = fmaf(v.y, v.y, a);
            a = fmaf(v.z, v.z, a); a = fmaf(v.w, v.w, a);
        }
        s_nrm[tid] = a;
    }
    __syncthreads();

    int t0 = wave * 64 + lane;
    int t1 = t0 + 256;
    const float4* xi0 = (const float4*)(dst + ((size_t)b * 512 + t0) * 32);
    const float4* xi1 = (const float4*)(dst + ((size_t)b * 512 + t1) * 32);
    float xd0[32], xd1[32];
#pragma unroll
    for (int q = 0; q < 8; q++) {
        float4 v = xi0[q];
        xd0[q*4+0] = v.x; xd0[q*4+1] = v.y; xd0[q*4+2] = v.z; xd0[q*4+3] = v.w;
        float4 w = xi1[q];
        xd1[q*4+0] = w.x; xd1[q*4+1] = w.y; xd1[q*4+2] = w.z; xd1[q*4+3] = w.w;
    }

    float val0[KNN], val1[KNN]; int idx0[KNN], idx1[KNN];
#pragma unroll
    for (int k = 0; k < KNN; k++) {
        val0[k] = 3.0e38f; idx0[k] = 0;
        val1[k] = 3.0e38f; idx1[k] = 0;
    }

    for (int s = 0; s < NS; s++) {
        float a0 = 0.f, a1 = 0.f, a2 = 0.f, a3 = 0.f;
        float c0 = 0.f, c1 = 0.f, c2 = 0.f, c3 = 0.f;
#pragma unroll
        for (int q = 0; q < 8; q++) {
            float4 v = s_src[s * 8 + q];
            a0 = fmaf(xd0[q*4+0], v.x, a0); a1 = fmaf(xd0[q*4+1], v.y, a1);
            a2 = fmaf(xd0[q*4+2], v.z, a2); a3 = fmaf(xd0[q*4+3], v.w, a3);
            c0 = fmaf(xd1[q*4+0], v.x, c0); c1 = fmaf(xd1[q*4+1], v.y, c1);
            c2 = fmaf(xd1[q*4+2], v.z, c2); c3 = fmaf(xd1[q*4+3], v.w, c3);
        }
        float nrm = s_nrm[s];
        float dv0 = nrm - 2.f * ((a0 + a1) + (a2 + a3));
        float dv1 = nrm - 2.f * ((c0 + c1) + (c2 + c3));
        ins8(dv0, s, val0, idx0);
        ins8(dv1, s, val1, idx1);
    }

    int* o0 = idx_out + ((size_t)b * 512 + t0) * 8;
    int* o1 = idx_out + ((size_t)b * 512 + t1) * 8;
#pragma unroll
    for (int k = 0; k < KNN; k++) { o0[k] = idx0[k]; o1[k] = idx1[k]; }
}

// ---------------- split kNN body (NS=512, 4-way src split) ----------------
// kid = (event<<2)|part. Block scans rows [part*128, part*128+128) for all
// 512 dst (2 per lane). Emits exact fp32 partial sorted top-8 + u16 global
// row indices; gather merges parts in ascending order (exact single-scan
// tie semantics). LDS 16.5KB -> 4 blocks/CU at grid 1024 = 16 waves/CU.
__device__ void knn_split_body(const float* __restrict__ src, const float* __restrict__ dst,
                               float* __restrict__ pval, unsigned int* __restrict__ pidx,
                               int kid)
{
    constexpr int HR = 128;
    __shared__ float4 s_src[HR * 8];
    __shared__ float  s_nrm[HR];
    int b = kid >> 2, part = kid & 3;
    int tid = threadIdx.x;
    int lane = tid & 63;
    int wave = tid >> 6;

    const float4* src4 = (const float4*)(src + ((size_t)b * 512 + part * HR) * 32);
    for (int i = tid; i < HR * 8; i += 256) s_src[i] = src4[i];
    __syncthreads();
    if (tid < HR) {
        float a = 0.f;
#pragma unroll
        for (int q = 0; q < 8; q++) {
            float4 v = s_src[tid * 8 + q];
            a = fmaf(v.x, v.x, a); a = fmaf(v.y, v.y, a);
            a = fmaf(v.z, v.z, a); a = fmaf(v.w, v.w, a);
        }
        s_nrm[tid] = a;
    }
    __syncthreads();

    int t0 = wave * 64 + lane;
    int t1 = t0 + 256;
    const float4* xi0 = (const float4*)(dst + ((size_t)b * 512 + t0) * 32);
    const float4* xi1 = (const float4*)(dst + ((size_t)b * 512 + t1) * 32);
    float xd0[32], xd1[32];
#pragma unroll
    for (int q = 0; q < 8; q++) {
        float4 v = xi0[q];
        xd0[q*4+0] = v.x; xd0[q*4+1] = v.y; xd0[q*4+2] = v.z; xd0[q*4+3] = v.w;
        float4 w = xi1[q];
        xd1[q*4+0] = w.x; xd1[q*4+1] = w.y; xd1[q*4+2] = w.z; xd1[q*4+3] = w.w;
    }

    float val0[KNN], val1[KNN]; int idx0[KNN], idx1[KNN];
#pragma unroll
    for (int k = 0; k < KNN; k++) {
        val0[k] = 3.0e38f; idx0[k] = 0;
        val1[k] = 3.0e38f; idx1[k] = 0;
    }

    for (int s = 0; s < HR; s++) {
        float a0 = 0.f, a1 = 0.f, a2 = 0.f, a3 = 0.f;
        float c0 = 0.f, c1 = 0.f, c2 = 0.f, c3 = 0.f;
#pragma unroll
        for (int q = 0; q < 8; q++) {
            float4 v = s_src[s * 8 + q];
            a0 = fmaf(xd0[q*4+0], v.x, a0); a1 = fmaf(xd0[q*4+1], v.y, a1);
            a2 = fmaf(xd0[q*4+2], v.z, a2); a3 = fmaf(xd0[q*4+3], v.w, a3);
            c0 = fmaf(xd1[q*4+0], v.x, c0); c1 = fmaf(xd1[q*4+1], v.y, c1);
            c2 = fmaf(xd1[q*4+2], v.z, c2); c3 = fmaf(xd1[q*4+3], v.w, c3);
        }
        float nrm = s_nrm[s];
        float dv0 = nrm - 2.f * ((a0 + a1) + (a2 + a3));
        float dv1 = nrm - 2.f * ((c0 + c1) + (c2 + c3));
        ins8(dv0, s, val0, idx0);
        ins8(dv1, s, val1, idx1);
    }

    int base = part * HR;
    {
        float* pv = pval + ((size_t)b * 512 + t0) * 32 + part * 8;
        unsigned int* pi = pidx + ((size_t)b * 512 + t0) * 16 + part * 4;
#pragma unroll
        for (int k = 0; k < KNN; k++) pv[k] = val0[k];
#pragma unroll
        for (int k = 0; k < 4; k++)
            pi[k] = (unsigned)(idx0[2*k] + base) | ((unsigned)(idx0[2*k+1] + base) << 16);
    }
    {
        float* pv = pval + ((size_t)b * 512 + t1) * 32 + part * 8;
        unsigned int* pi = pidx + ((size_t)b * 512 + t1) * 16 + part * 4;
#pragma unroll
        for (int k = 0; k < KNN; k++) pv[k] = val1[k];
#pragma unroll
        for (int k = 0; k < 4; k++)
            pi[k] = (unsigned)(idx1[2*k] + base) | ((unsigned)(idx1[2*k+1] + base) << 16);
    }
}

// ---------------- fused conv1: knn_small + Y/Base (interleaved roles) -----
__global__ __launch_bounds__(256) void fused_conv1_kernel(
    const float* __restrict__ sv_enc, const float* __restrict__ trk_enc,
    int* __restrict__ knn_idx,
    const float* __restrict__ w2h, const float* __restrict__ wd, const float* __restrict__ bb,
    float* __restrict__ Ybuf, float* __restrict__ f1)
{
    int bid = blockIdx.x;            // 2560 = 256 knn + 2304 yb, interleaved %10
    int r = bid % 10;
    if (r == 0) {
        knn_small_body(sv_enc, trk_enc, knn_idx, bid / 10);
    } else {
        int yid = (bid / 10) * 9 + (r - 1);     // [0, 2304)
        if (yid < 256) yb_body(sv_enc, w2h, nullptr, Ybuf, yid * 64);
        else           yb_body(trk_enc, wd, bb, f1, (yid - 256) * 64);
    }
}

// ---------------- fused convN: split kNN + Y/Base (interleaved roles) -----
__global__ __launch_bounds__(256) void fused_convN_kernel(
    const float* __restrict__ src, const float* __restrict__ dst,
    float* __restrict__ pval, unsigned int* __restrict__ pidx,
    const float* __restrict__ w2h, const float* __restrict__ wd, const float* __restrict__ bb,
    float* __restrict__ Ybuf, float* __restrict__ fout)
{
    int bid = blockIdx.x;            // 5120 = 1024 knn + 4096 yb, interleaved %5
    int r = bid % 5;
    if (r == 0) {
        knn_split_body(src, dst, pval, pidx, bid / 5);
    } else {
        int yid = (bid / 5) * 4 + (r - 1);      // [0, 4096)
        if (yid < 2048) yb_body(src, w2h, nullptr, Ybuf, yid * 64);
        else            yb_body(dst, wd, bb, fout, (yid - 2048) * 64);
    }
}

// ---------------- gather (+4-part merge) + max + elu, in-place on f -------
template<bool MERGE>
__global__ __launch_bounds__(256) void gather_kernel(
    const float* __restrict__ Y,
    const int* __restrict__ nbr,
    const float* __restrict__ pval, const unsigned int* __restrict__ pidx,
    float* __restrict__ f, int NSs)
{
    int t = blockIdx.x * 256 + threadIdx.x;
    int e = t >> 9;
    int rows[8];
    if (MERGE) {
        const float4* pv = (const float4*)(pval + (size_t)t * 32);
        const uint4*  pu = (const uint4*)(pidx + (size_t)t * 16);
        float4 v0 = pv[0], v1 = pv[1];
        uint4  u0 = pu[0];
        float val[8] = { v0.x, v0.y, v0.z, v0.w, v1.x, v1.y, v1.z, v1.w };
        int   idx[8] = { (int)(u0.x & 0xffff), (int)(u0.x >> 16),
                         (int)(u0.y & 0xffff), (int)(u0.y >> 16),
                         (int)(u0.z & 0xffff), (int)(u0.z >> 16),
                         (int)(u0.w & 0xffff), (int)(u0.w >> 16) };
#pragma unroll
        for (int p = 1; p < 4; p++) {
            float4 a = pv[2*p], b = pv[2*p+1];
            uint4  u = pu[p];
            float cva[8] = { a.x, a.y, a.z, a.w, b.x, b.y, b.z, b.w };
            int   cia[8] = { (int)(u.x & 0xffff), (int)(u.x >> 16),
                             (int)(u.y & 0xffff), (int)(u.y >> 16),
                             (int)(u.z & 0xffff), (int)(u.z >> 16),
                             (int)(u.w & 0xffff), (int)(u.w >> 16) };
#pragma unroll
            for (int j = 0; j < 8; j++) ins8(cva[j], cia[j], val, idx);
        }
#pragma unroll
        for (int k = 0; k < 8; k++) rows[k] = idx[k];
    } else {
        const int4* ip = (const int4*)(nbr + (size_t)t * 8);
        int4 i0 = ip[0], i1 = ip[1];
        rows[0] = i0.x; rows[1] = i0.y; rows[2] = i0.z; rows[3] = i0.w;
        rows[4] = i1.x; rows[5] = i1.y; rows[6] = i1.z; rows[7] = i1.w;
    }

    const float4* Yb = (const float4*)(Y + (size_t)e * NSs * 32);
    float4 m[8];
    {
        const float4* rr = Yb + (size_t)rows[0] * 8;
#pragma unroll
        for (int q = 0; q < 8; q++) m[q] = rr[q];
    }
#pragma unroll
    for (int k = 1; k < 8; k++) {
        const float4* rr = Yb + (size_t)rows[k] * 8;
#pragma unroll
        for (int q = 0; q < 8; q++) {
            float4 v = rr[q];
            m[q].x = fmaxf(m[q].x, v.x); m[q].y = fmaxf(m[q].y, v.y);
            m[q].z = fmaxf(m[q].z, v.z); m[q].w = fmaxf(m[q].w, v.w);
        }
    }
    float4* op = (float4*)(f + (size_t)t * 32);
#pragma unroll
    for (int q = 0; q < 8; q++) {
        float4 bv = op[q];
        float4 o;
        o.x = elu_f(bv.x + m[q].x); o.y = elu_f(bv.y + m[q].y);
        o.z = elu_f(bv.z + m[q].z); o.w = elu_f(bv.w + m[q].w);
        op[q] = o;
    }
}

// ---------------- mean pool + out MLP + sigmoid + arange ----------------
__global__ __launch_bounds__(64) void final_kernel(
    const float* __restrict__ f3,
    const float* __restrict__ W1, const float* __restrict__ b1,
    const float* __restrict__ W2, const float* __restrict__ b2,
    float* __restrict__ outp)
{
    int b = blockIdx.x;
    int lane = threadIdx.x;
    int c = lane & 31, hh = lane >> 5;
    const float* base = f3 + (size_t)b * 512 * 32;
    float s = 0.f;
    for (int r = hh; r < 512; r += 2) s += base[r * 32 + c];
    s += __shfl_xor(s, 32);
    float pooled = s * (1.0f / 512.0f);
    __shared__ float sp[32];
    __shared__ float sh1[32];
    if (lane < 32) sp[c] = pooled;
    __syncthreads();
    if (lane < 32) {
        float h = b1[c];
#pragma unroll
        for (int d = 0; d < 32; d++) h = fmaf(sp[d], W1[d * 32 + c], h);
        sh1[c] = elu_f(h);
    }
    __syncthreads();
    if (lane == 0) {
        float o = b2[0];
#pragma unroll
        for (int d = 0; d < 32; d++) o = fmaf(sh1[d], W2[d], o);
        o = 1.f / (1.f + __expf(-o));
        outp[b] = o;
        outp[NB + b] = (float)b;
    }
}

extern "C" void kernel_launch(void* const* d_in, const int* in_sizes, int n_in,
                              void* d_out, int out_size, void* d_ws, size_t ws_size,
                              hipStream_t stream) {
    const float* x_sv  = (const float*)d_in[0];
    const float* x_trk = (const float*)d_in[1];
    const float* x_pfc = (const float*)d_in[2];
    const float* sv_W1  = (const float*)d_in[6];
    const float* sv_b1  = (const float*)d_in[7];
    const float* sv_W2  = (const float*)d_in[8];
    const float* sv_b2  = (const float*)d_in[9];
    const float* trk_W1 = (const float*)d_in[10];
    const float* trk_b1 = (const float*)d_in[11];
    const float* trk_W2 = (const float*)d_in[12];
    const float* trk_b2 = (const float*)d_in[13];
    const float* pfc_W1 = (const float*)d_in[14];
    const float* pfc_b1 = (const float*)d_in[15];
    const float* pfc_W2 = (const float*)d_in[16];
    const float* pfc_b2 = (const float*)d_in[17];
    const float* conv_W = (const float*)d_in[18];
    const float* conv_b = (const float*)d_in[19];
    const float* out_W1 = (const float*)d_in[20];
    const float* out_b1 = (const float*)d_in[21];
    const float* out_W2 = (const float*)d_in[22];
    const float* out_b2 = (const float*)d_in[23];

    float* ws = (float*)d_ws;
    const size_t SV_E  = (size_t)NB * NSV * HD;    //   524288
    const size_t TRK_E = (size_t)NB * NTRK * HD;   //  4194304
    float* sv_enc  = ws;
    float* trk_enc = sv_enc + SV_E;
    float* pfc_enc = trk_enc + TRK_E;
    float* f1      = pfc_enc + TRK_E;
    float* f2      = f1 + TRK_E;
    float* wd      = f2 + TRK_E;
    float* w2h     = wd + 1024;
    float* bb      = w2h + 1024;
    // pval region (conv2/3) aliases conv1's int32 knn_idx (disjoint lifetime)
    float* pval    = bb + 64;                                  // NB*512*32 floats
    int*   knn_idx = (int*)pval;                               // NB*512*8 ints
    unsigned int* pidx = (unsigned int*)(pval + (size_t)NB * 512 * 32);  // NB*512*16 u32
    float* Ybuf    = (float*)(pidx + (size_t)NB * 512 * 16);
    float* f3      = trk_enc;  // trk_enc dead after conv2 -> reuse

    const int gblocks = (NB * 512) / 256;   // 512

    encode_all_kernel<<<8705, 256, 0, stream>>>(
        x_sv, x_trk, x_pfc,
        sv_W1, sv_b1, sv_W2, sv_b2,
        trk_W1, trk_b1, trk_W2, trk_b2,
        pfc_W1, pfc_b1, pfc_W2, pfc_b2,
        conv_W, conv_b,
        sv_enc, trk_enc, pfc_enc, wd, w2h, bb);

    // conv1: sv -> trk
    fused_conv1_kernel<<<2560, 256, 0, stream>>>(sv_enc, trk_enc, knn_idx, w2h, wd, bb, Ybuf, f1);
    gather_kernel<false><<<gblocks, 256, 0, stream>>>(Ybuf, knn_idx, nullptr, nullptr, f1, NSV);
    // conv2: pfc -> trk
    fused_convN_kernel<<<5120, 256, 0, stream>>>(pfc_enc, trk_enc, pval, pidx, w2h, wd, bb, Ybuf, f2);
    gather_kernel<true><<<gblocks, 256, 0, stream>>>(Ybuf, nullptr, pval, pidx, f2, NPFC);
    // conv3: f1 -> f2
    fused_convN_kernel<<<5120, 256, 0, stream>>>(f1, f2, pval, pidx, w2h, wd, bb, Ybuf, f3);
    gather_kernel<true><<<gblocks, 256, 0, stream>>>(Ybuf, nullptr, pval, pidx, f3, NTRK);

    final_kernel<<<NB, 64, 0, stream>>>(f3, out_W1, out_b1, out_W2, out_b2, (float*)d_out);
}

// Round 10
// 649.690 us; speedup vs baseline: 1.1109x; 1.1109x over previous
//
#include <hip/hip_runtime.h>
#include <math.h>

#define NB 256      // events
#define NSV 64
#define NTRK 512
#define NPFC 512
#define KNN 8
#define HD 32

__device__ __forceinline__ float elu_f(float x) {
    return x > 0.f ? x : __expf(x) - 1.f;
}

// Branchless sorted top-8 insert (ascending val, lower-index tie-break via
// strict <; ascending-s scan order). Flat v_cmp + v_cndmask codegen.
__device__ __forceinline__ void ins8(float dv, int s, float* val, int* idx) {
    bool c0 = dv < val[0], c1 = dv < val[1], c2 = dv < val[2], c3 = dv < val[3];
    bool c4 = dv < val[4], c5 = dv < val[5], c6 = dv < val[6], c7 = dv < val[7];
    val[7] = c6 ? val[6] : (c7 ? dv : val[7]);
    idx[7] = c6 ? idx[6] : (c7 ? s  : idx[7]);
    val[6] = c5 ? val[5] : (c6 ? dv : val[6]);
    idx[6] = c5 ? idx[5] : (c6 ? s  : idx[6]);
    val[5] = c4 ? val[4] : (c5 ? dv : val[5]);
    idx[5] = c4 ? idx[4] : (c5 ? s  : idx[5]);
    val[4] = c3 ? val[3] : (c4 ? dv : val[4]);
    idx[4] = c3 ? idx[3] : (c4 ? s  : idx[4]);
    val[3] = c2 ? val[2] : (c3 ? dv : val[3]);
    idx[3] = c2 ? idx[2] : (c3 ? s  : idx[3]);
    val[2] = c1 ? val[1] : (c2 ? dv : val[2]);
    idx[2] = c1 ? idx[1] : (c2 ? s  : idx[2]);
    val[1] = c0 ? val[0] : (c1 ? dv : val[1]);
    idx[1] = c0 ? idx[0] : (c1 ? s  : idx[1]);
    val[0] = c0 ? dv : val[0];
    idx[0] = c0 ? s  : idx[0];
}

// ---------------- encoder body ----------------
template<int FIN>
__device__ void encode_body(const float* __restrict__ x,
                            const float* __restrict__ W1, const float* __restrict__ b1,
                            const float* __restrict__ W2, const float* __restrict__ b2,
                            float* __restrict__ out, int blk, int n_nodes)
{
    __shared__ float sW1[FIN * 32];
    __shared__ float sW2[32 * 32];
    __shared__ float sb1[32], sb2[32];
    __shared__ float sx[8][FIN];
    __shared__ float sh[8][32];
    int tid = threadIdx.x;
    for (int i = tid; i < FIN * 32; i += 256) sW1[i] = W1[i];
    for (int i = tid; i < 32 * 32; i += 256) sW2[i] = W2[i];
    if (tid < 32) { sb1[tid] = b1[tid]; sb2[tid] = b2[tid]; }
    int ln = tid >> 5, c = tid & 31;
    for (int it = 0; it < 4; it++) {
        int node0 = blk * 32 + it * 8;
        __syncthreads();
        for (int i = tid; i < 8 * FIN; i += 256) {
            int nn = i / FIN, f = i - nn * FIN;
            int node = node0 + nn;
            sx[nn][f] = (node < n_nodes) ? x[(size_t)node * FIN + f] : 0.f;
        }
        __syncthreads();
        float h = sb1[c];
#pragma unroll
        for (int f = 0; f < FIN; f++) h = fmaf(sx[ln][f], sW1[f * 32 + c], h);
        h = elu_f(h);
        sh[ln][c] = h;
        __syncthreads();
        float o = sb2[c];
#pragma unroll
        for (int k = 0; k < 32; k++) o = fmaf(sh[ln][k], sW2[k * 32 + c], o);
        o = elu_f(o);
        int node = node0 + ln;
        if (node < n_nodes) out[(size_t)node * 32 + c] = o;
    }
}

// ---------------- fused encoders + weight prep (1 launch) ----------------
__global__ __launch_bounds__(256) void encode_all_kernel(
    const float* __restrict__ x_sv, const float* __restrict__ x_trk, const float* __restrict__ x_pfc,
    const float* __restrict__ sv_W1, const float* __restrict__ sv_b1,
    const float* __restrict__ sv_W2, const float* __restrict__ sv_b2,
    const float* __restrict__ trk_W1, const float* __restrict__ trk_b1,
    const float* __restrict__ trk_W2, const float* __restrict__ trk_b2,
    const float* __restrict__ pfc_W1, const float* __restrict__ pfc_b1,
    const float* __restrict__ pfc_W2, const float* __restrict__ pfc_b2,
    const float* __restrict__ conv_W, const float* __restrict__ conv_b,
    float* __restrict__ sv_enc, float* __restrict__ trk_enc, float* __restrict__ pfc_enc,
    float* __restrict__ wd, float* __restrict__ w2h, float* __restrict__ bb)
{
    int bid = blockIdx.x;
    if (bid < 512) {
        encode_body<14>(x_sv, sv_W1, sv_b1, sv_W2, sv_b2, sv_enc, bid, NB * NSV);
    } else if (bid < 4608) {
        encode_body<30>(x_trk, trk_W1, trk_b1, trk_W2, trk_b2, trk_enc, bid - 512, NB * NTRK);
    } else if (bid < 8704) {
        encode_body<10>(x_pfc, pfc_W1, pfc_b1, pfc_W2, pfc_b2, pfc_enc, bid - 4608, NB * NPFC);
    } else {
        int tid = threadIdx.x;
        for (int i = tid; i < 1024; i += 256) {
            float lo = conv_W[i], hi = conv_W[1024 + i];
            wd[i] = lo - hi;
            w2h[i] = hi;
        }
        if (tid < 32) bb[tid] = conv_b[tid];
    }
}

// ---------------- small kNN body (NS=64, one block per event) -------------
__device__ void knn_small_body(const float* __restrict__ src, const float* __restrict__ dst,
                               int* __restrict__ idx_out, int b)
{
    constexpr int NS = 64;
    __shared__ float4 s_src[NS * 8];
    __shared__ float  s_nrm[NS];
    int tid = threadIdx.x;
    int lane = tid & 63;
    int wave = tid >> 6;

    const float4* src4 = (const float4*)(src + (size_t)b * NS * 32);
    for (int i = tid; i < NS * 8; i += 256) s_src[i] = src4[i];
    __syncthreads();
    if (tid < NS) {
        float a = 0.f;
#pragma unroll
        for (int q = 0; q < 8; q++) {
            float4 v = s_src[tid * 8 + q];
            a = fmaf(v.x, v.x, a); a = fmaf(v.y, v.y, a);
            a = fmaf(v.z, v.z, a); a = fmaf(v.w, v.w, a);
        }
        s_nrm[tid] = a;
    }
    __syncthreads();

    int t0 = wave * 64 + lane;
    int t1 = t0 + 256;
    const float4* xi0 = (const float4*)(dst + ((size_t)b * 512 + t0) * 32);
    const float4* xi1 = (const float4*)(dst + ((size_t)b * 512 + t1) * 32);
    float xd0[32], xd1[32];
#pragma unroll
    for (int q = 0; q < 8; q++) {
        float4 v = xi0[q];
        xd0[q*4+0] = v.x; xd0[q*4+1] = v.y; xd0[q*4+2] = v.z; xd0[q*4+3] = v.w;
        float4 w = xi1[q];
        xd1[q*4+0] = w.x; xd1[q*4+1] = w.y; xd1[q*4+2] = w.z; xd1[q*4+3] = w.w;
    }

    float val0[KNN], val1[KNN]; int idx0[KNN], idx1[KNN];
#pragma unroll
    for (int k = 0; k < KNN; k++) {
        val0[k] = 3.0e38f; idx0[k] = 0;
        val1[k] = 3.0e38f; idx1[k] = 0;
    }

    for (int s = 0; s < NS; s++) {
        float a0 = 0.f, a1 = 0.f, a2 = 0.f, a3 = 0.f;
        float c0 = 0.f, c1 = 0.f, c2 = 0.f, c3 = 0.f;
#pragma unroll
        for (int q = 0; q < 8; q++) {
            float4 v = s_src[s * 8 + q];
            a0 = fmaf(xd0[q*4+0], v.x, a0); a1 = fmaf(xd0[q*4+1], v.y, a1);
            a2 = fmaf(xd0[q*4+2], v.z, a2); a3 = fmaf(xd0[q*4+3], v.w, a3);
            c0 = fmaf(xd1[q*4+0], v.x, c0); c1 = fmaf(xd1[q*4+1], v.y, c1);
            c2 = fmaf(xd1[q*4+2], v.z, c2); c3 = fmaf(xd1[q*4+3], v.w, c3);
        }
        float nrm = s_nrm[s];
        float dv0 = nrm - 2.f * ((a0 + a1) + (a2 + a3));
        float dv1 = nrm - 2.f * ((c0 + c1) + (c2 + c3));
        ins8(dv0, s, val0, idx0);
        ins8(dv1, s, val1, idx1);
    }

    int* o0 = idx_out + ((size_t)b * 512 + t0) * 8;
    int* o1 = idx_out + ((size_t)b * 512 + t1) * 8;
#pragma unroll
    for (int k = 0; k < KNN; k++) { o0[k] = idx0[k]; o1[k] = idx1[k]; }
}

// ---------------- split kNN body (NS=512, 4-way src split) ----------------
__device__ void knn_split_body(const float* __restrict__ src, const float* __restrict__ dst,
                               float* __restrict__ pval, unsigned int* __restrict__ pidx,
                               int kid)
{
    constexpr int HR = 128;
    __shared__ float4 s_src[HR * 8];
    __shared__ float  s_nrm[HR];
    int b = kid >> 2, part = kid & 3;
    int tid = threadIdx.x;
    int lane = tid & 63;
    int wave = tid >> 6;

    const float4* src4 = (const float4*)(src + ((size_t)b * 512 + part * HR) * 32);
    for (int i = tid; i < HR * 8; i += 256) s_src[i] = src4[i];
    __syncthreads();
    if (tid < HR) {
        float a = 0.f;
#pragma unroll
        for (int q = 0; q < 8; q++) {
            float4 v = s_src[tid * 8 + q];
            a = fmaf(v.x, v.x, a); a = fmaf(v.y, v.y, a);
            a = fmaf(v.z, v.z, a); a = fmaf(v.w, v.w, a);
        }
        s_nrm[tid] = a;
    }
    __syncthreads();

    int t0 = wave * 64 + lane;
    int t1 = t0 + 256;
    const float4* xi0 = (const float4*)(dst + ((size_t)b * 512 + t0) * 32);
    const float4* xi1 = (const float4*)(dst + ((size_t)b * 512 + t1) * 32);
    float xd0[32], xd1[32];
#pragma unroll
    for (int q = 0; q < 8; q++) {
        float4 v = xi0[q];
        xd0[q*4+0] = v.x; xd0[q*4+1] = v.y; xd0[q*4+2] = v.z; xd0[q*4+3] = v.w;
        float4 w = xi1[q];
        xd1[q*4+0] = w.x; xd1[q*4+1] = w.y; xd1[q*4+2] = w.z; xd1[q*4+3] = w.w;
    }

    float val0[KNN], val1[KNN]; int idx0[KNN], idx1[KNN];
#pragma unroll
    for (int k = 0; k < KNN; k++) {
        val0[k] = 3.0e38f; idx0[k] = 0;
        val1[k] = 3.0e38f; idx1[k] = 0;
    }

    for (int s = 0; s < HR; s++) {
        float a0 = 0.f, a1 = 0.f, a2 = 0.f, a3 = 0.f;
        float c0 = 0.f, c1 = 0.f, c2 = 0.f, c3 = 0.f;
#pragma unroll
        for (int q = 0; q < 8; q++) {
            float4 v = s_src[s * 8 + q];
            a0 = fmaf(xd0[q*4+0], v.x, a0); a1 = fmaf(xd0[q*4+1], v.y, a1);
            a2 = fmaf(xd0[q*4+2], v.z, a2); a3 = fmaf(xd0[q*4+3], v.w, a3);
            c0 = fmaf(xd1[q*4+0], v.x, c0); c1 = fmaf(xd1[q*4+1], v.y, c1);
            c2 = fmaf(xd1[q*4+2], v.z, c2); c3 = fmaf(xd1[q*4+3], v.w, c3);
        }
        float nrm = s_nrm[s];
        float dv0 = nrm - 2.f * ((a0 + a1) + (a2 + a3));
        float dv1 = nrm - 2.f * ((c0 + c1) + (c2 + c3));
        ins8(dv0, s, val0, idx0);
        ins8(dv1, s, val1, idx1);
    }

    int base = part * HR;
    {
        float* pv = pval + ((size_t)b * 512 + t0) * 32 + part * 8;
        unsigned int* pi = pidx + ((size_t)b * 512 + t0) * 16 + part * 4;
#pragma unroll
        for (int k = 0; k < KNN; k++) pv[k] = val0[k];
#pragma unroll
        for (int k = 0; k < 4; k++)
            pi[k] = (unsigned)(idx0[2*k] + base) | ((unsigned)(idx0[2*k+1] + base) << 16);
    }
    {
        float* pv = pval + ((size_t)b * 512 + t1) * 32 + part * 8;
        unsigned int* pi = pidx + ((size_t)b * 512 + t1) * 16 + part * 4;
#pragma unroll
        for (int k = 0; k < KNN; k++) pv[k] = val1[k];
#pragma unroll
        for (int k = 0; k < 4; k++)
            pi[k] = (unsigned)(idx1[2*k] + base) | ((unsigned)(idx1[2*k+1] + base) << 16);
    }
}

// ---------------- knn12: conv1 small + conv2 split, homogeneous fusion ----
// Both bodies are register-fat VALU kernels with the same profile — safe to
// share one kernel (unlike r9's knn+yb mix which let the lean yb path set an
// 80-VGPR cap and cripple the knn path). Interleave %5 balances CUs.
__global__ __launch_bounds__(256) void knn12_kernel(
    const float* __restrict__ sv_enc, const float* __restrict__ trk_enc,
    const float* __restrict__ pfc_enc,
    int* __restrict__ knn_idx,
    float* __restrict__ pval, unsigned int* __restrict__ pidx)
{
    int bid = blockIdx.x;            // 1280 = 256 small + 1024 split
    int r = bid % 5;
    if (r == 0) knn_small_body(sv_enc, trk_enc, knn_idx, bid / 5);
    else        knn_split_body(pfc_enc, trk_enc, pval, pidx, (bid / 5) * 4 + (r - 1));
}

__global__ __launch_bounds__(256) void knn3_kernel(
    const float* __restrict__ f1, const float* __restrict__ f2,
    float* __restrict__ pval, unsigned int* __restrict__ pidx)
{
    knn_split_body(f1, f2, pval, pidx, blockIdx.x);
}

// ---------------- Y/Base GEMM body + all-in-one launches ------------------
__device__ void yb_body(const float* __restrict__ X, const float* __restrict__ W,
                        const float* __restrict__ bias, float* __restrict__ O, int rb)
{
    __shared__ float sW[1024];
    __shared__ float sb[32];
    __shared__ float sx[8][32];
    int tid = threadIdx.x;
    for (int i = tid; i < 1024; i += 256) sW[i] = W[i];
    if (tid < 32) sb[tid] = bias ? bias[tid] : 0.f;
    int ln = tid >> 5, c = tid & 31;
    for (int p = 0; p < 8; p++) {
        __syncthreads();
        sx[ln][c] = X[(size_t)(rb + p * 8 + ln) * 32 + c];
        __syncthreads();
        float acc = sb[c];
#pragma unroll
        for (int d = 0; d < 32; d++) acc = fmaf(sx[ln][d], sW[d * 32 + c], acc);
        O[(size_t)(rb + p * 8 + ln) * 32 + c] = acc;
    }
}

// 6400 blocks: Y1(256) | B1(2048) | Y2(2048) | B2(2048)
__global__ __launch_bounds__(256) void yb12_kernel(
    const float* __restrict__ sv_enc, const float* __restrict__ trk_enc,
    const float* __restrict__ pfc_enc,
    const float* __restrict__ w2h, const float* __restrict__ wd, const float* __restrict__ bb,
    float* __restrict__ Y1, float* __restrict__ f1,
    float* __restrict__ Y2, float* __restrict__ f2)
{
    int bid = blockIdx.x;
    if (bid < 256)       yb_body(sv_enc,  w2h, nullptr, Y1, bid * 64);
    else if (bid < 2304) yb_body(trk_enc, wd,  bb,      f1, (bid - 256) * 64);
    else if (bid < 4352) yb_body(pfc_enc, w2h, nullptr, Y2, (bid - 2304) * 64);
    else                 yb_body(trk_enc, wd,  bb,      f2, (bid - 4352) * 64);
}

// 4096 blocks: Y3(2048) | B3(2048)
__global__ __launch_bounds__(256) void yb3_kernel(
    const float* __restrict__ f1, const float* __restrict__ f2,
    const float* __restrict__ w2h, const float* __restrict__ wd, const float* __restrict__ bb,
    float* __restrict__ Y3, float* __restrict__ f3)
{
    int bid = blockIdx.x;
    if (bid < 2048) yb_body(f1, w2h, nullptr, Y3, bid * 64);
    else            yb_body(f2, wd,  bb,      f3, (bid - 2048) * 64);
}

// ---------------- gather body: (merge) + max + elu, in-place on f ---------
template<bool MERGE>
__device__ void gather_body(
    const float* __restrict__ Y,
    const int* __restrict__ nbr,
    const float* __restrict__ pval, const unsigned int* __restrict__ pidx,
    float* __restrict__ f, int NSs, int t)
{
    int e = t >> 9;
    int rows[8];
    if (MERGE) {
        const float4* pv = (const float4*)(pval + (size_t)t * 32);
        const uint4*  pu = (const uint4*)(pidx + (size_t)t * 16);
        float4 v0 = pv[0], v1 = pv[1];
        uint4  u0 = pu[0];
        float val[8] = { v0.x, v0.y, v0.z, v0.w, v1.x, v1.y, v1.z, v1.w };
        int   idx[8] = { (int)(u0.x & 0xffff), (int)(u0.x >> 16),
                         (int)(u0.y & 0xffff), (int)(u0.y >> 16),
                         (int)(u0.z & 0xffff), (int)(u0.z >> 16),
                         (int)(u0.w & 0xffff), (int)(u0.w >> 16) };
#pragma unroll
        for (int p = 1; p < 4; p++) {
            float4 a = pv[2*p], b = pv[2*p+1];
            uint4  u = pu[p];
            float cva[8] = { a.x, a.y, a.z, a.w, b.x, b.y, b.z, b.w };
            int   cia[8] = { (int)(u.x & 0xffff), (int)(u.x >> 16),
                             (int)(u.y & 0xffff), (int)(u.y >> 16),
                             (int)(u.z & 0xffff), (int)(u.z >> 16),
                             (int)(u.w & 0xffff), (int)(u.w >> 16) };
#pragma unroll
            for (int j = 0; j < 8; j++) ins8(cva[j], cia[j], val, idx);
        }
#pragma unroll
        for (int k = 0; k < 8; k++) rows[k] = idx[k];
    } else {
        const int4* ip = (const int4*)(nbr + (size_t)t * 8);
        int4 i0 = ip[0], i1 = ip[1];
        rows[0] = i0.x; rows[1] = i0.y; rows[2] = i0.z; rows[3] = i0.w;
        rows[4] = i1.x; rows[5] = i1.y; rows[6] = i1.z; rows[7] = i1.w;
    }

    const float4* Yb = (const float4*)(Y + (size_t)e * NSs * 32);
    float4 m[8];
    {
        const float4* rr = Yb + (size_t)rows[0] * 8;
#pragma unroll
        for (int q = 0; q < 8; q++) m[q] = rr[q];
    }
#pragma unroll
    for (int k = 1; k < 8; k++) {
        const float4* rr = Yb + (size_t)rows[k] * 8;
#pragma unroll
        for (int q = 0; q < 8; q++) {
            float4 v = rr[q];
            m[q].x = fmaxf(m[q].x, v.x); m[q].y = fmaxf(m[q].y, v.y);
            m[q].z = fmaxf(m[q].z, v.z); m[q].w = fmaxf(m[q].w, v.w);
        }
    }
    float4* op = (float4*)(f + (size_t)t * 32);
#pragma unroll
    for (int q = 0; q < 8; q++) {
        float4 bv = op[q];
        float4 o;
        o.x = elu_f(bv.x + m[q].x); o.y = elu_f(bv.y + m[q].y);
        o.z = elu_f(bv.z + m[q].z); o.w = elu_f(bv.w + m[q].w);
        op[q] = o;
    }
}

// 1024 blocks: conv1 gather (512, no-merge) + conv2 gather (512, merge)
__global__ __launch_bounds__(256) void g12_kernel(
    const float* __restrict__ Y1, const int* __restrict__ knn_idx, float* __restrict__ f1,
    const float* __restrict__ Y2, const float* __restrict__ pval,
    const unsigned int* __restrict__ pidx, float* __restrict__ f2)
{
    int bid = blockIdx.x;
    if (bid < 512) {
        int t = bid * 256 + threadIdx.x;
        gather_body<false>(Y1, knn_idx, nullptr, nullptr, f1, NSV, t);
    } else {
        int t = (bid - 512) * 256 + threadIdx.x;
        gather_body<true>(Y2, nullptr, pval, pidx, f2, NPFC, t);
    }
}

__global__ __launch_bounds__(256) void g3_kernel(
    const float* __restrict__ Y3, const float* __restrict__ pval,
    const unsigned int* __restrict__ pidx, float* __restrict__ f3)
{
    int t = blockIdx.x * 256 + threadIdx.x;
    gather_body<true>(Y3, nullptr, pval, pidx, f3, NTRK, t);
}

// ---------------- mean pool + out MLP + sigmoid + arange ----------------
__global__ __launch_bounds__(64) void final_kernel(
    const float* __restrict__ f3,
    const float* __restrict__ W1, const float* __restrict__ b1,
    const float* __restrict__ W2, const float* __restrict__ b2,
    float* __restrict__ outp)
{
    int b = blockIdx.x;
    int lane = threadIdx.x;
    int c = lane & 31, hh = lane >> 5;
    const float* base = f3 + (size_t)b * 512 * 32;
    float s = 0.f;
    for (int r = hh; r < 512; r += 2) s += base[r * 32 + c];
    s += __shfl_xor(s, 32);
    float pooled = s * (1.0f / 512.0f);
    __shared__ float sp[32];
    __shared__ float sh1[32];
    if (lane < 32) sp[c] = pooled;
    __syncthreads();
    if (lane < 32) {
        float h = b1[c];
#pragma unroll
        for (int d = 0; d < 32; d++) h = fmaf(sp[d], W1[d * 32 + c], h);
        sh1[c] = elu_f(h);
    }
    __syncthreads();
    if (lane == 0) {
        float o = b2[0];
#pragma unroll
        for (int d = 0; d < 32; d++) o = fmaf(sh1[d], W2[d], o);
        o = 1.f / (1.f + __expf(-o));
        outp[b] = o;
        outp[NB + b] = (float)b;
    }
}

extern "C" void kernel_launch(void* const* d_in, const int* in_sizes, int n_in,
                              void* d_out, int out_size, void* d_ws, size_t ws_size,
                              hipStream_t stream) {
    const float* x_sv  = (const float*)d_in[0];
    const float* x_trk = (const float*)d_in[1];
    const float* x_pfc = (const float*)d_in[2];
    const float* sv_W1  = (const float*)d_in[6];
    const float* sv_b1  = (const float*)d_in[7];
    const float* sv_W2  = (const float*)d_in[8];
    const float* sv_b2  = (const float*)d_in[9];
    const float* trk_W1 = (const float*)d_in[10];
    const float* trk_b1 = (const float*)d_in[11];
    const float* trk_W2 = (const float*)d_in[12];
    const float* trk_b2 = (const float*)d_in[13];
    const float* pfc_W1 = (const float*)d_in[14];
    const float* pfc_b1 = (const float*)d_in[15];
    const float* pfc_W2 = (const float*)d_in[16];
    const float* pfc_b2 = (const float*)d_in[17];
    const float* conv_W = (const float*)d_in[18];
    const float* conv_b = (const float*)d_in[19];
    const float* out_W1 = (const float*)d_in[20];
    const float* out_b1 = (const float*)d_in[21];
    const float* out_W2 = (const float*)d_in[22];
    const float* out_b2 = (const float*)d_in[23];

    float* ws = (float*)d_ws;
    const size_t SV_E  = (size_t)NB * NSV * HD;    //   524288
    const size_t TRK_E = (size_t)NB * NTRK * HD;   //  4194304
    float* sv_enc  = ws;
    float* trk_enc = sv_enc + SV_E;
    float* pfc_enc = trk_enc + TRK_E;
    float* f1      = pfc_enc + TRK_E;
    float* f2      = f1 + TRK_E;
    float* wd      = f2 + TRK_E;
    float* w2h     = wd + 1024;
    float* bb      = w2h + 1024;
    float* pval    = bb + 64;                                  // NB*512*32 floats
    unsigned int* pidx = (unsigned int*)(pval + TRK_E);        // NB*512*16 u32
    int*   knn_idx = (int*)(pidx + (size_t)NB * 512 * 16);     // NB*512*8 ints
    float* Y1buf   = (float*)(knn_idx + (size_t)NB * 512 * 8); // NB*64*32
    float* Y2buf   = Y1buf + SV_E;                             // NB*512*32
    float* f3      = trk_enc;  // trk_enc dead after yb12 -> reuse

    encode_all_kernel<<<8705, 256, 0, stream>>>(
        x_sv, x_trk, x_pfc,
        sv_W1, sv_b1, sv_W2, sv_b2,
        trk_W1, trk_b1, trk_W2, trk_b2,
        pfc_W1, pfc_b1, pfc_W2, pfc_b2,
        conv_W, conv_b,
        sv_enc, trk_enc, pfc_enc, wd, w2h, bb);

    knn12_kernel<<<1280, 256, 0, stream>>>(sv_enc, trk_enc, pfc_enc, knn_idx, pval, pidx);
    yb12_kernel<<<6400, 256, 0, stream>>>(sv_enc, trk_enc, pfc_enc, w2h, wd, bb,
                                          Y1buf, f1, Y2buf, f2);
    g12_kernel<<<1024, 256, 0, stream>>>(Y1buf, knn_idx, f1, Y2buf, pval, pidx, f2);

    knn3_kernel<<<1024, 256, 0, stream>>>(f1, f2, pval, pidx);
    yb3_kernel<<<4096, 256, 0, stream>>>(f1, f2, w2h, wd, bb, Y2buf, f3);
    g3_kernel<<<512, 256, 0, stream>>>(Y2buf, pval, pidx, f3);

    final_kernel<<<NB, 64, 0, stream>>>(f3, out_W1, out_b1, out_W2, out_b2, (float*)d_out);
}